// Round 11
// baseline (615.118 us; speedup 1.0000x reference)
//
#include <hip/hip_runtime.h>

typedef float    f32x4  __attribute__((ext_vector_type(4)));
typedef float    f32x16 __attribute__((ext_vector_type(16)));
typedef _Float16 f16x8  __attribute__((ext_vector_type(8)));
typedef _Float16 f16x4  __attribute__((ext_vector_type(4)));

#define T_TOK 4096
#define HD    1024
#define ID    4096
#define NE    8
#define TOTP  (2*T_TOK)
#define MAXT1 72
#define MAXT2 40     // BM=256 tiles (gemm1 + gemm2)

// ---- workspace layout (bytes). Total ~295 MB ----
#define WS_CNT   0
#define WS_FILL  64
#define WS_OFF   128
#define WS_TOT   192
#define WS_TOT2  196
#define WS_TEXP  256
#define WS_TM0   (256 + 4*MAXT1)
#define WS_TEXP2 (256 + 8*MAXT1)
#define WS_TM02  (256 + 8*MAXT1 + 4*MAXT2)
#define WS_TOPE  2048
#define WS_TOPW  (WS_TOPE + 4*TOTP)
#define WS_PAIR  (WS_TOPW + 4*TOTP)
#define WS_ACT   ((size_t)1 << 20)                              // f16[TOTP*ID]   64 MB
constexpr size_t WS_YBUF = WS_ACT  + 2ull*TOTP*ID;              // (spare)        16 MB
constexpr size_t WS_HS16 = WS_YBUF + 2ull*TOTP*HD;              // f16[T*HD]       8 MB
constexpr size_t WS_WG16 = WS_HS16 + 2ull*T_TOK*HD;             // f16[E][I][H]   67 MB
constexpr size_t WS_WU16 = WS_WG16 + 2ull*NE*HD*ID;             // f16[E][I][H]   67 MB
constexpr size_t WS_WD16 = WS_WU16 + 2ull*NE*HD*ID;             // f16[E][H][I]   67 MB
// 2 ybuf K-split partials overlay the Wg16 region (dead after gemm1)
constexpr size_t WS_YB   = WS_WG16;                             // f16[2][TOTP*HD]

// async global->LDS, 16B per lane, wave-uniform LDS base
__device__ __forceinline__ void gll16(const void* g, void* l) {
  __builtin_amdgcn_global_load_lds(
      (const __attribute__((address_space(1))) unsigned int*)g,
      (__attribute__((address_space(3))) unsigned int*)l, 16, 0, 0);
}

#define WAITV(N) do { \
    asm volatile("s_waitcnt vmcnt(" #N ")" ::: "memory"); \
    __builtin_amdgcn_sched_barrier(0); \
  } while (0)

// ---------------- routing ----------------
__global__ void k_router(const float* __restrict__ logits, char* __restrict__ ws) {
  int t = blockIdx.x * blockDim.x + threadIdx.x;
  if (t >= T_TOK) return;
  float v0 = -1e30f, v1 = -1e30f; int i0 = 0, i1 = 0;
  #pragma unroll
  for (int e = 0; e < NE; ++e) {
    float v = logits[t * NE + e];
    if (v > v0)      { v1 = v0; i1 = i0; v0 = v; i0 = e; }
    else if (v > v1) { v1 = v;  i1 = e; }
  }
  float w0 = 1.f / (1.f + __expf(v1 - v0));
  ((int*)(ws + WS_TOPE))[2*t]   = i0;
  ((int*)(ws + WS_TOPE))[2*t+1] = i1;
  ((float*)(ws + WS_TOPW))[2*t]   = w0;
  ((float*)(ws + WS_TOPW))[2*t+1] = 1.f - w0;
  atomicAdd(&((int*)(ws + WS_CNT))[i0], 1);
  atomicAdd(&((int*)(ws + WS_CNT))[i1], 1);
}

__global__ void k_prefix(char* __restrict__ ws) {
  if (threadIdx.x != 0 || blockIdx.x != 0) return;
  const int* cnt = (const int*)(ws + WS_CNT);
  int* off   = (int*)(ws + WS_OFF);
  int* texp  = (int*)(ws + WS_TEXP);
  int* tm0   = (int*)(ws + WS_TM0);
  int* texp2 = (int*)(ws + WS_TEXP2);
  int* tm02  = (int*)(ws + WS_TM02);
  int run = 0, t1 = 0, t2 = 0;
  for (int e = 0; e < NE; ++e) {
    off[e] = run;
    int ne = cnt[e];
    for (int i = 0; i < ne; i += 128) { texp[t1] = e; tm0[t1] = i; ++t1; }
    for (int i = 0; i < ne; i += 256) { texp2[t2] = e; tm02[t2] = i; ++t2; }
    run += ne;
  }
  off[NE] = run;
  *(int*)(ws + WS_TOT)  = t1;
  *(int*)(ws + WS_TOT2) = t2;
}

__global__ void k_scatter(char* __restrict__ ws) {
  int t = blockIdx.x * blockDim.x + threadIdx.x;
  if (t >= T_TOK) return;
  const int* tope = (const int*)(ws + WS_TOPE);
  const int* off  = (const int*)(ws + WS_OFF);
  int* fill = (int*)(ws + WS_FILL);
  int* pair = (int*)(ws + WS_PAIR);
  #pragma unroll
  for (int s = 0; s < 2; ++s) {
    int id = 2*t + s;
    int e = tope[id];
    int pos = off[e] + atomicAdd(&fill[e], 1);
    pair[pos] = id;   // order nondeterministic; ybuf row = id keeps output deterministic
  }
}

// ---------------- conversions ----------------
__global__ void k_hscvt(const float* __restrict__ src, _Float16* __restrict__ dst) {
  int i = blockIdx.x * blockDim.x + threadIdx.x;
  f32x4 v = ((const f32x4*)src)[i];
  f16x4 o;
  #pragma unroll
  for (int j = 0; j < 4; ++j) o[j] = (_Float16)v[j];
  ((f16x4*)dst)[i] = o;
}

// f32 [e][K][N] -> f16 [e][N][K], 64x64 tiles via LDS
__global__ __launch_bounds__(256) void k_wtrans(const float* __restrict__ src,
                                                _Float16* __restrict__ dst,
                                                int K, int N) {
  const int e = blockIdx.z;
  const int n0 = blockIdx.x * 64, k0 = blockIdx.y * 64;
  const float* s = src + (size_t)e * K * N;
  _Float16* d = dst + (size_t)e * (size_t)K * N;
  __shared__ _Float16 t[64][68];
  const int tx = threadIdx.x & 15, ty = threadIdx.x >> 4;
  #pragma unroll
  for (int it = 0; it < 4; ++it) {
    int k = k0 + it*16 + ty;
    f32x4 v = *(const f32x4*)&s[(size_t)k * N + n0 + tx*4];
    #pragma unroll
    for (int j = 0; j < 4; ++j) t[tx*4 + j][it*16 + ty] = (_Float16)v[j];
  }
  __syncthreads();
  #pragma unroll
  for (int it = 0; it < 4; ++it) {
    int n = it*16 + ty;
    *(f16x4*)&d[(size_t)(n0 + n) * K + k0 + tx*4] = *(const f16x4*)&t[n][tx*4];
  }
}

// ---------------- GEMM1: act[p] = silu(hs@Wg) * (hs@Wu), f16 ----------------
// 32x32x16 MFMA + granule-major LDS (conflict-free by construction).
// BM=256, BN=128 dual-B, BK=64; 8 waves (2M x 4N); 128 KB dbuf;
// drain-0 + 1 barrier per K-tile. Wave w stages granule w of A/Bg/Bu.
__global__ __launch_bounds__(512, 2) void k_gemm1(
    const _Float16* __restrict__ hs16, const _Float16* __restrict__ WgT,
    const _Float16* __restrict__ WuT, char* __restrict__ ws) {
  const int s = blockIdx.y;
  if (s >= *(const int*)(ws + WS_TOT2)) return;
  const int e    = ((const int*)(ws + WS_TEXP2))[s];
  const int m0   = ((const int*)(ws + WS_TM02))[s];
  const int offE = ((const int*)(ws + WS_OFF))[e];
  const int nE   = ((const int*)(ws + WS_CNT))[e];
  _Float16* __restrict__ act = (_Float16*)(ws + WS_ACT);
  const int n0 = blockIdx.x * 128;
  const int tid = threadIdx.x, lane = tid & 63, wid = tid >> 6;

  // per buffer (f16 idx), granule-major:
  //   A [g:8][row:256][8]  @0      (16384)
  //   Bg[g:8][row:128][8]  @16384  (8192)
  //   Bu[g:8][row:128][8]  @24576  (8192)
  __shared__ __align__(16) _Float16 sm[2 * 32768];   // 128 KB

  const int* __restrict__ pairp = (const int*)(ws + WS_PAIR);
  const _Float16 *aP[4], *gP[2], *uP[2];
  #pragma unroll
  for (int c = 0; c < 4; ++c) {        // A rows 64c+lane, granule wid
    int mm = m0 + 64*c + lane;
    int tok = (mm < nE) ? (pairp[offE + mm] >> 1) : 0;
    aP[c] = hs16 + (size_t)tok * HD + wid * 8;
  }
  #pragma unroll
  for (int c = 0; c < 2; ++c) {        // B cols 64c+lane, granule wid
    size_t col = (size_t)e * ID + (n0 + 64*c + lane);
    gP[c] = WgT + col * HD + wid * 8;
    uP[c] = WuT + col * HD + wid * 8;
  }

  auto stage8 = [&](int buf, int kt) {   // 8 gll/wave/K-tile, 1 KB contiguous each
    _Float16* base = sm + buf * 32768;
    const int ko = kt * 64;
    #pragma unroll
    for (int c = 0; c < 4; ++c)
      gll16(aP[c] + ko, base + wid*2048 + c*512);
    #pragma unroll
    for (int c = 0; c < 2; ++c) {
      gll16(gP[c] + ko, base + 16384 + wid*1024 + c*512);
      gll16(uP[c] + ko, base + 24576 + wid*1024 + c*512);
    }
  };

  const int wr = wid >> 2, wc = wid & 3;       // 2M x 4N
  const int l31 = lane & 31, kh = lane >> 5;   // 32x32 operand: row/col=lane&31
  f32x16 accg[4] = {}, accu[4] = {};

  auto computeKK = [&](int buf, int kk) {  // K=16 step: 6 b128 reads, 8 MFMA(32x32)
    const _Float16* b0 = sm + buf * 32768;
    const int g = kk*2 + kh;               // granule holding this lane's k-half
    f16x8 afr[4], bgf, buf_;
    #pragma unroll
    for (int i = 0; i < 4; ++i)            // lanes 0-31: contiguous 512B
      afr[i] = *(const f16x8*)&b0[g*2048 + (128*wr + 32*i + l31) * 8];
    bgf  = *(const f16x8*)&b0[16384 + g*1024 + (32*wc + l31) * 8];
    buf_ = *(const f16x8*)&b0[24576 + g*1024 + (32*wc + l31) * 8];
    __builtin_amdgcn_s_setprio(1);
    #pragma unroll
    for (int i = 0; i < 4; ++i) {
      accg[i] = __builtin_amdgcn_mfma_f32_32x32x16_f16(afr[i], bgf,  accg[i], 0, 0, 0);
      accu[i] = __builtin_amdgcn_mfma_f32_32x32x16_f16(afr[i], buf_, accu[i], 0, 0, 0);
    }
    __builtin_amdgcn_s_setprio(0);
  };

  const int KT = HD / 64;                  // 16
  stage8(0, 0);
  WAITV(0);
  __builtin_amdgcn_s_barrier();
  for (int t = 0; t < KT; ++t) {
    const int cur = t & 1;
    if (t + 1 < KT) stage8(cur ^ 1, t + 1);  // issue early; retires under MFMA
    computeKK(cur, 0); computeKK(cur, 1);
    computeKK(cur, 2); computeKK(cur, 3);
    WAITV(0);                                // next tile fully landed
    __builtin_amdgcn_s_barrier();            // + everyone done reading cur
  }

  // C/D 32x32: col = lane&31, row = (reg&3) + 8*(reg>>2) + 4*(lane>>5)
  #pragma unroll
  for (int i = 0; i < 4; ++i)
    #pragma unroll
    for (int r = 0; r < 16; ++r) {
      const int row = (r & 3) + 8 * (r >> 2) + 4 * kh;
      const int mm = m0 + 128*wr + 32*i + row;
      if (mm < nE) {
        float g = accg[i][r], u = accu[i][r];
        float sv = g / (1.f + __expf(-g)) * u;
        act[(size_t)(offE + mm) * ID + n0 + 32*wc + l31] = (_Float16)sv;
      }
    }
}

// ---------------- GEMM2: yb[h][id] = act[p][kh] @ WdT[e][kh] (K-split 2) -----
// Same structure: BM=256, BN=256, BK=64; 8 waves (2M x 4N); 32x32x16 MFMA;
// granule-major LDS; 128 KB dbuf; drain-0 + 1 barrier per K-tile.
__global__ __launch_bounds__(512, 2) void k_gemm2(const _Float16* __restrict__ WdT,
                                                  char* __restrict__ ws) {
  const int s = blockIdx.y;
  if (s >= *(const int*)(ws + WS_TOT2)) return;
  const int e    = ((const int*)(ws + WS_TEXP2))[s];
  const int m0   = ((const int*)(ws + WS_TM02))[s];
  const int offE = ((const int*)(ws + WS_OFF))[e];
  const int nE   = ((const int*)(ws + WS_CNT))[e];
  const int h    = blockIdx.z;             // K half
  const int kbase = h * (ID / 2);
  const int* __restrict__ pair = (const int*)(ws + WS_PAIR);
  const _Float16* __restrict__ act = (const _Float16*)(ws + WS_ACT);
  _Float16* __restrict__ yb = (_Float16*)(ws + WS_YB) + (size_t)h * TOTP * HD;
  const int n0 = blockIdx.x * 256;
  const int tid = threadIdx.x, lane = tid & 63, wid = tid >> 6;

  // per buffer (f16 idx), granule-major:
  //   A[g:8][row:256][8] @0 (16384) | B[g:8][row:256][8] @16384 (16384)
  __shared__ __align__(16) _Float16 sm[2 * 32768];   // 128 KB

  const _Float16 *aP[4], *bP[4];
  #pragma unroll
  for (int c = 0; c < 4; ++c) {        // A rows 64c+lane, granule wid
    int mm = m0 + 64*c + lane;
    int p = (mm < nE) ? (offE + mm) : offE;   // act rows ARE pair positions
    aP[c] = act + (size_t)p * ID + kbase + wid * 8;
  }
  #pragma unroll
  for (int c = 0; c < 4; ++c)          // B cols 64c+lane, granule wid
    bP[c] = WdT + ((size_t)e * HD + (n0 + 64*c + lane)) * ID + kbase + wid * 8;

  auto stage8 = [&](int buf, int kt) {   // 8 gll/wave/K-tile, 1 KB contiguous each
    _Float16* base = sm + buf * 32768;
    const int ko = kt * 64;
    #pragma unroll
    for (int c = 0; c < 4; ++c)
      gll16(aP[c] + ko, base + wid*2048 + c*512);
    #pragma unroll
    for (int c = 0; c < 4; ++c)
      gll16(bP[c] + ko, base + 16384 + wid*2048 + c*512);
  };

  const int wr = wid >> 2, wc = wid & 3;   // 2M x 4N
  const int l31 = lane & 31, kh = lane >> 5;
  f32x16 acc[4][2] = {};

  auto computeKK = [&](int buf, int kk) {  // K=16 step: 6 b128 reads, 8 MFMA(32x32)
    const _Float16* b0 = sm + buf * 32768;
    const int g = kk*2 + kh;
    f16x8 afr[4], bfr[2];
    #pragma unroll
    for (int i = 0; i < 4; ++i)
      afr[i] = *(const f16x8*)&b0[g*2048 + (128*wr + 32*i + l31) * 8];
    #pragma unroll
    for (int j = 0; j < 2; ++j)
      bfr[j] = *(const f16x8*)&b0[16384 + g*2048 + (64*wc + 32*j + l31) * 8];
    __builtin_amdgcn_s_setprio(1);
    #pragma unroll
    for (int i = 0; i < 4; ++i)
      #pragma unroll
      for (int j = 0; j < 2; ++j)
        acc[i][j] = __builtin_amdgcn_mfma_f32_32x32x16_f16(afr[i], bfr[j], acc[i][j], 0, 0, 0);
    __builtin_amdgcn_s_setprio(0);
  };

  const int KT = (ID / 2) / 64;            // 32
  stage8(0, 0);
  WAITV(0);
  __builtin_amdgcn_s_barrier();
  for (int t = 0; t < KT; ++t) {
    const int cur = t & 1;
    if (t + 1 < KT) stage8(cur ^ 1, t + 1);
    computeKK(cur, 0); computeKK(cur, 1);
    computeKK(cur, 2); computeKK(cur, 3);
    WAITV(0);
    __builtin_amdgcn_s_barrier();
  }

  #pragma unroll
  for (int i = 0; i < 4; ++i)
    #pragma unroll
    for (int r = 0; r < 16; ++r) {
      const int row = (r & 3) + 8 * (r >> 2) + 4 * kh;
      const int mm = m0 + 128*wr + 32*i + row;
      if (mm < nE) {
        const int id = pair[offE + mm];
        #pragma unroll
        for (int j = 0; j < 2; ++j)
          yb[(size_t)id * HD + n0 + 64*wc + 32*j + l31] = (_Float16)acc[i][j][r];
      }
    }
}

// ---------------- combine: out[t] = w0*sum_h(y[h][2t]) + w1*sum_h(y[h][2t+1])
__global__ void k_combine(const char* __restrict__ ws, float* __restrict__ out) {
  const int idx = blockIdx.x * blockDim.x + threadIdx.x;   // over T*HD/8
  const int t = idx >> 7, c = idx & 127;
  const float* topw = (const float*)(ws + WS_TOPW);
  const _Float16* yb = (const _Float16*)(ws + WS_YB);
  float s0[8] = {}, s1[8] = {};
  #pragma unroll
  for (int h = 0; h < 2; ++h) {
    const _Float16* p = yb + (size_t)h * TOTP * HD;
    f16x8 y0 = ((const f16x8*)(p + (size_t)(2*t)     * HD))[c];
    f16x8 y1 = ((const f16x8*)(p + (size_t)(2*t + 1) * HD))[c];
    #pragma unroll
    for (int j = 0; j < 8; ++j) { s0[j] += (float)y0[j]; s1[j] += (float)y1[j]; }
  }
  const float w0 = topw[2*t], w1 = topw[2*t+1];
  f32x4 o0, o1;
  #pragma unroll
  for (int j = 0; j < 4; ++j) {
    o0[j] = w0 * s0[j]     + w1 * s1[j];
    o1[j] = w0 * s0[4 + j] + w1 * s1[4 + j];
  }
  ((f32x4*)out)[2*idx]     = o0;
  ((f32x4*)out)[2*idx + 1] = o1;
}

extern "C" void kernel_launch(void* const* d_in, const int* in_sizes, int n_in,
                              void* d_out, int out_size, void* d_ws, size_t ws_size,
                              hipStream_t stream) {
  const float* hs     = (const float*)d_in[0];
  const float* logits = (const float*)d_in[1];
  const float* Wg     = (const float*)d_in[2];
  const float* Wu     = (const float*)d_in[3];
  const float* Wd     = (const float*)d_in[4];
  char* ws = (char*)d_ws;   // requires ~295 MB of workspace

  _Float16* hs16 = (_Float16*)(ws + WS_HS16);
  _Float16* wg16 = (_Float16*)(ws + WS_WG16);
  _Float16* wu16 = (_Float16*)(ws + WS_WU16);
  _Float16* wd16 = (_Float16*)(ws + WS_WD16);

  hipMemsetAsync(ws, 0, 256, stream);
  k_router <<<dim3(T_TOK/256), dim3(256), 0, stream>>>(logits, ws);
  k_prefix <<<dim3(1),         dim3(64),  0, stream>>>(ws);
  k_scatter<<<dim3(T_TOK/256), dim3(256), 0, stream>>>(ws);
  k_hscvt  <<<dim3(T_TOK*HD/4/256), dim3(256), 0, stream>>>(hs, hs16);
  k_wtrans <<<dim3(ID/64, HD/64, NE), dim3(256), 0, stream>>>(Wg, wg16, HD, ID);
  k_wtrans <<<dim3(ID/64, HD/64, NE), dim3(256), 0, stream>>>(Wu, wu16, HD, ID);
  k_wtrans <<<dim3(HD/64, ID/64, NE), dim3(256), 0, stream>>>(Wd, wd16, ID, HD);
  k_gemm1  <<<dim3(ID/128, MAXT2),    dim3(512), 0, stream>>>(hs16, wg16, wu16, ws);
  k_gemm2  <<<dim3(HD/256, MAXT2, 2), dim3(512), 0, stream>>>(wd16, ws);
  k_combine<<<dim3(T_TOK*HD/8/256), dim3(256), 0, stream>>>(ws, (float*)d_out);
}

// Round 12
// 505.778 us; speedup vs baseline: 1.2162x; 1.2162x over previous
//
#include <hip/hip_runtime.h>

typedef float    f32x4 __attribute__((ext_vector_type(4)));
typedef _Float16 f16x8 __attribute__((ext_vector_type(8)));
typedef _Float16 f16x4 __attribute__((ext_vector_type(4)));

#define T_TOK 4096
#define HD    1024
#define ID    4096
#define NE    8
#define TOTP  (2*T_TOK)
#define MAXT1 72
#define MAXT2 40     // BM=256 tiles (gemm1 + gemm2)

// ---- workspace layout (bytes). Total ~295 MB ----
#define WS_CNT   0
#define WS_FILL  64
#define WS_OFF   128
#define WS_TOT   192
#define WS_TOT2  196
#define WS_TEXP  256
#define WS_TM0   (256 + 4*MAXT1)
#define WS_TEXP2 (256 + 8*MAXT1)
#define WS_TM02  (256 + 8*MAXT1 + 4*MAXT2)
#define WS_TOPE  2048
#define WS_TOPW  (WS_TOPE + 4*TOTP)
#define WS_PAIR  (WS_TOPW + 4*TOTP)
#define WS_ACT   ((size_t)1 << 20)                              // f16[TOTP*ID]   64 MB
constexpr size_t WS_YBUF = WS_ACT  + 2ull*TOTP*ID;              // (spare)        16 MB
constexpr size_t WS_HS16 = WS_YBUF + 2ull*TOTP*HD;              // f16[T*HD]       8 MB
constexpr size_t WS_WG16 = WS_HS16 + 2ull*T_TOK*HD;             // f16[E][I][H]   67 MB
constexpr size_t WS_WU16 = WS_WG16 + 2ull*NE*HD*ID;             // f16[E][I][H]   67 MB
constexpr size_t WS_WD16 = WS_WU16 + 2ull*NE*HD*ID;             // f16[E][H][I]   67 MB
// 4 ybuf K-split partials overlay the Wg16 region (dead after gemm1): exact fit
constexpr size_t WS_YB   = WS_WG16;                             // f16[4][TOTP*HD]

// async global->LDS, 16B per lane, wave-uniform LDS base
__device__ __forceinline__ void gll16(const void* g, void* l) {
  __builtin_amdgcn_global_load_lds(
      (const __attribute__((address_space(1))) unsigned int*)g,
      (__attribute__((address_space(3))) unsigned int*)l, 16, 0, 0);
}

#define WAITV(N) do { \
    asm volatile("s_waitcnt vmcnt(" #N ")" ::: "memory"); \
    __builtin_amdgcn_sched_barrier(0); \
  } while (0)

// [row][64] f16 tile swizzle (BK=64): 8 granules XOR row&7 (bases 8-aligned)
__device__ __forceinline__ int lofs64(int row, int g8) {
  return row * 64 + ((g8 ^ (row & 7)) << 3);
}

// ---------------- routing ----------------
__global__ void k_router(const float* __restrict__ logits, char* __restrict__ ws) {
  int t = blockIdx.x * blockDim.x + threadIdx.x;
  if (t >= T_TOK) return;
  float v0 = -1e30f, v1 = -1e30f; int i0 = 0, i1 = 0;
  #pragma unroll
  for (int e = 0; e < NE; ++e) {
    float v = logits[t * NE + e];
    if (v > v0)      { v1 = v0; i1 = i0; v0 = v; i0 = e; }
    else if (v > v1) { v1 = v;  i1 = e; }
  }
  float w0 = 1.f / (1.f + __expf(v1 - v0));
  ((int*)(ws + WS_TOPE))[2*t]   = i0;
  ((int*)(ws + WS_TOPE))[2*t+1] = i1;
  ((float*)(ws + WS_TOPW))[2*t]   = w0;
  ((float*)(ws + WS_TOPW))[2*t+1] = 1.f - w0;
  atomicAdd(&((int*)(ws + WS_CNT))[i0], 1);
  atomicAdd(&((int*)(ws + WS_CNT))[i1], 1);
}

__global__ void k_prefix(char* __restrict__ ws) {
  if (threadIdx.x != 0 || blockIdx.x != 0) return;
  const int* cnt = (const int*)(ws + WS_CNT);
  int* off   = (int*)(ws + WS_OFF);
  int* texp  = (int*)(ws + WS_TEXP);
  int* tm0   = (int*)(ws + WS_TM0);
  int* texp2 = (int*)(ws + WS_TEXP2);
  int* tm02  = (int*)(ws + WS_TM02);
  int run = 0, t1 = 0, t2 = 0;
  for (int e = 0; e < NE; ++e) {
    off[e] = run;
    int ne = cnt[e];
    for (int i = 0; i < ne; i += 128) { texp[t1] = e; tm0[t1] = i; ++t1; }
    for (int i = 0; i < ne; i += 256) { texp2[t2] = e; tm02[t2] = i; ++t2; }
    run += ne;
  }
  off[NE] = run;
  *(int*)(ws + WS_TOT)  = t1;
  *(int*)(ws + WS_TOT2) = t2;
}

__global__ void k_scatter(char* __restrict__ ws) {
  int t = blockIdx.x * blockDim.x + threadIdx.x;
  if (t >= T_TOK) return;
  const int* tope = (const int*)(ws + WS_TOPE);
  const int* off  = (const int*)(ws + WS_OFF);
  int* fill = (int*)(ws + WS_FILL);
  int* pair = (int*)(ws + WS_PAIR);
  #pragma unroll
  for (int s = 0; s < 2; ++s) {
    int id = 2*t + s;
    int e = tope[id];
    int pos = off[e] + atomicAdd(&fill[e], 1);
    pair[pos] = id;   // order nondeterministic; ybuf row = id keeps output deterministic
  }
}

// ---------------- conversions ----------------
__global__ void k_hscvt(const float* __restrict__ src, _Float16* __restrict__ dst) {
  int i = blockIdx.x * blockDim.x + threadIdx.x;   // over T*HD/8
  f32x4 a = ((const f32x4*)src)[2*i];
  f32x4 b = ((const f32x4*)src)[2*i + 1];
  f16x8 o;
  #pragma unroll
  for (int j = 0; j < 4; ++j) { o[j] = (_Float16)a[j]; o[4 + j] = (_Float16)b[j]; }
  ((f16x8*)dst)[i] = o;
}

// f32 [e][K][N] -> f16 [e][N][K], 64x64 tiles via LDS; 16B reads AND writes
__global__ __launch_bounds__(256) void k_wtrans(const float* __restrict__ src,
                                                _Float16* __restrict__ dst,
                                                int K, int N) {
  const int e = blockIdx.z;
  const int n0 = blockIdx.x * 64, k0 = blockIdx.y * 64;
  const float* s = src + (size_t)e * K * N;
  _Float16* d = dst + (size_t)e * (size_t)K * N;
  __shared__ _Float16 t[64][72];   // 144B row stride: f16x8 reads stay 16B-aligned
  const int tx = threadIdx.x & 15, ty = threadIdx.x >> 4;
  #pragma unroll
  for (int it = 0; it < 4; ++it) {
    int k = k0 + it*16 + ty;
    f32x4 v = *(const f32x4*)&s[(size_t)k * N + n0 + tx*4];
    #pragma unroll
    for (int j = 0; j < 4; ++j) t[tx*4 + j][it*16 + ty] = (_Float16)v[j];
  }
  __syncthreads();
  const int n2 = threadIdx.x >> 3, sg = threadIdx.x & 7;
  #pragma unroll
  for (int it = 0; it < 2; ++it) {
    int n = it*32 + n2;
    *(f16x8*)&d[(size_t)(n0 + n) * K + k0 + sg*8] = *(const f16x8*)&t[n][sg*8];
  }
}

// ---------------- GEMM1: act[p] = silu(hs@Wg) * (hs@Wu), f16 ----------------
// (R9 structure, measured 177 us / MfmaUtil 38%)
// BM=256, BN=128 dual-B, BK=64; 8 waves (2M x 4N), wave tile 128x32 for g AND u.
__global__ __launch_bounds__(512, 2) void k_gemm1(
    const _Float16* __restrict__ hs16, const _Float16* __restrict__ WgT,
    const _Float16* __restrict__ WuT, char* __restrict__ ws) {
  const int s = blockIdx.y;
  if (s >= *(const int*)(ws + WS_TOT2)) return;
  const int e    = ((const int*)(ws + WS_TEXP2))[s];
  const int m0   = ((const int*)(ws + WS_TM02))[s];
  const int offE = ((const int*)(ws + WS_OFF))[e];
  const int nE   = ((const int*)(ws + WS_CNT))[e];
  _Float16* __restrict__ act = (_Float16*)(ws + WS_ACT);
  const int n0 = blockIdx.x * 128;
  const int tid = threadIdx.x, lane = tid & 63, wid = tid >> 6;

  // per buffer (f16 idx): A[256][64] @0 | Bg[128][64] @16384 | Bu[128][64] @24576
  __shared__ __align__(16) _Float16 sm[2 * 32768];   // 128 KB

  const int r8 = lane >> 3;
  const int q64 = (((lane & 7) ^ r8) << 3);   // inverse-swizzled source granule
  const int* __restrict__ pairp = (const int*)(ws + WS_PAIR);
  const _Float16 *aP[4], *gP[2], *uP[2];
  #pragma unroll
  for (int c = 0; c < 4; ++c) {        // A: wave stages rows 32w..32w+31
    int mm = m0 + 32*wid + 8*c + r8;
    int tok = (mm < nE) ? (pairp[offE + mm] >> 1) : 0;
    aP[c] = hs16 + (size_t)tok * HD + q64;
  }
  #pragma unroll
  for (int c = 0; c < 2; ++c) {        // B: wave stages cols 16w..16w+15
    size_t col = (size_t)e * ID + (n0 + 16*wid + 8*c + r8);
    gP[c] = WgT + col * HD + q64;
    uP[c] = WuT + col * HD + q64;
  }

  auto stage8 = [&](int buf, int kt) {   // 8 gll per wave per K-tile (128B lines)
    _Float16* base = sm + buf * 32768;
    const int ko = kt * 64;
    #pragma unroll
    for (int c = 0; c < 4; ++c)
      gll16(aP[c] + ko, base + (32*wid + 8*c) * 64);
    #pragma unroll
    for (int c = 0; c < 2; ++c) {
      gll16(gP[c] + ko, base + 16384 + (16*wid + 8*c) * 64);
      gll16(uP[c] + ko, base + 24576 + (16*wid + 8*c) * 64);
    }
  };

  const int wr = wid >> 2, wc = wid & 3;   // 2M x 4N
  const int l15 = lane & 15, l4 = lane >> 4;
  f32x4 accg[8][2] = {}, accu[8][2] = {};

  auto computeKK = [&](int buf, int kk) {  // one K=32 half: 12 reads, 32 MFMA
    const _Float16* b0 = sm + buf * 32768;
    f16x8 afr[8], bg[2], bu[2];
    #pragma unroll
    for (int i = 0; i < 8; ++i) {
      const int row = 128*wr + 16*i + l15;
      afr[i] = *(const f16x8*)&b0[lofs64(row, kk*4 + l4)];
    }
    #pragma unroll
    for (int j = 0; j < 2; ++j) {
      const int row = 32*wc + 16*j + l15;
      bg[j] = *(const f16x8*)&b0[16384 + lofs64(row, kk*4 + l4)];
      bu[j] = *(const f16x8*)&b0[24576 + lofs64(row, kk*4 + l4)];
    }
    __builtin_amdgcn_s_setprio(1);
    #pragma unroll
    for (int i = 0; i < 8; ++i)
      #pragma unroll
      for (int j = 0; j < 2; ++j) {
        accg[i][j] = __builtin_amdgcn_mfma_f32_16x16x32_f16(afr[i], bg[j], accg[i][j], 0, 0, 0);
        accu[i][j] = __builtin_amdgcn_mfma_f32_16x16x32_f16(afr[i], bu[j], accu[i][j], 0, 0, 0);
      }
    __builtin_amdgcn_s_setprio(0);
  };

  const int KT = HD / 64;                  // 16
  stage8(0, 0);
  WAITV(0);
  __builtin_amdgcn_s_barrier();
  for (int t = 0; t < KT; ++t) {
    const int cur = t & 1;
    if (t + 1 < KT) stage8(cur ^ 1, t + 1);  // issue early; retires under MFMA
    computeKK(cur, 0);
    computeKK(cur, 1);
    WAITV(0);                                // next tile fully landed
    __builtin_amdgcn_s_barrier();            // + everyone done reading cur
  }

  #pragma unroll
  for (int i = 0; i < 8; ++i)
    #pragma unroll
    for (int r = 0; r < 4; ++r) {
      const int mm = m0 + 128*wr + 16*i + 4*l4 + r;   // C/D: col=lane&15, row=(lane>>4)*4+r
      if (mm < nE) {
        const size_t prow = (size_t)(offE + mm) * ID;
        #pragma unroll
        for (int j = 0; j < 2; ++j) {
          float g = accg[i][j][r], u = accu[i][j][r];
          float sv = g / (1.f + __expf(-g)) * u;
          act[prow + n0 + 32*wc + 16*j + l15] = (_Float16)sv;
        }
      }
    }
}

// ---------------- GEMM2: yb[h][id] = act[p][kq] @ WdT[e][kq] (K-split 4) -----
// gemm1's proven shape at BN=128: BM=256, BK=64; 8 waves (2M x 4N), wave tile
// 128x32; 96 KB dbuf; 8*34*4 ~ 1088 blocks -> fine-grained makespan (+18% not +41%).
__global__ __launch_bounds__(512, 2) void k_gemm2(const _Float16* __restrict__ WdT,
                                                  char* __restrict__ ws) {
  const int s = blockIdx.y;
  if (s >= *(const int*)(ws + WS_TOT2)) return;
  const int e    = ((const int*)(ws + WS_TEXP2))[s];
  const int m0   = ((const int*)(ws + WS_TM02))[s];
  const int offE = ((const int*)(ws + WS_OFF))[e];
  const int nE   = ((const int*)(ws + WS_CNT))[e];
  const int h    = blockIdx.z;             // K quarter
  const int kbase = h * (ID / 4);
  const int* __restrict__ pair = (const int*)(ws + WS_PAIR);
  const _Float16* __restrict__ act = (const _Float16*)(ws + WS_ACT);
  _Float16* __restrict__ yb = (_Float16*)(ws + WS_YB) + (size_t)h * TOTP * HD;
  const int n0 = blockIdx.x * 128;
  const int tid = threadIdx.x, lane = tid & 63, wid = tid >> 6;

  // per buffer (f16 idx): A[256][64] @0 | B[128][64] @16384  -> 48 KB, dbuf 96 KB
  __shared__ __align__(16) _Float16 sm[2 * 24576];

  const int r8 = lane >> 3;
  const int q64 = (((lane & 7) ^ r8) << 3);
  const _Float16 *aP[4], *bP[2];
  #pragma unroll
  for (int c = 0; c < 4; ++c) {        // A: wave stages rows 32w..32w+31
    int mm = m0 + 32*wid + 8*c + r8;
    int p = (mm < nE) ? (offE + mm) : offE;   // act rows ARE pair positions
    aP[c] = act + (size_t)p * ID + kbase + q64;
  }
  #pragma unroll
  for (int c = 0; c < 2; ++c)          // B: wave stages cols 16w..16w+15
    bP[c] = WdT + ((size_t)e * HD + (n0 + 16*wid + 8*c + r8)) * ID + kbase + q64;

  auto stage6 = [&](int buf, int kt) {   // 6 gll per wave per K-tile (128B lines)
    _Float16* base = sm + buf * 24576;
    const int ko = kt * 64;
    #pragma unroll
    for (int c = 0; c < 4; ++c)
      gll16(aP[c] + ko, base + (32*wid + 8*c) * 64);
    #pragma unroll
    for (int c = 0; c < 2; ++c)
      gll16(bP[c] + ko, base + 16384 + (16*wid + 8*c) * 64);
  };

  const int wr = wid >> 2, wc = wid & 3;   // 2M x 4N
  const int l15 = lane & 15, l4 = lane >> 4;
  f32x4 acc[8][2] = {};

  auto computeKK = [&](int buf, int kk) {  // one K=32 half: 10 reads, 16 MFMA
    const _Float16* b0 = sm + buf * 24576;
    f16x8 afr[8], bfr[2];
    #pragma unroll
    for (int i = 0; i < 8; ++i)
      afr[i] = *(const f16x8*)&b0[lofs64(128*wr + 16*i + l15, kk*4 + l4)];
    #pragma unroll
    for (int j = 0; j < 2; ++j)
      bfr[j] = *(const f16x8*)&b0[16384 + lofs64(32*wc + 16*j + l15, kk*4 + l4)];
    __builtin_amdgcn_s_setprio(1);
    #pragma unroll
    for (int i = 0; i < 8; ++i)
      #pragma unroll
      for (int j = 0; j < 2; ++j)
        acc[i][j] = __builtin_amdgcn_mfma_f32_16x16x32_f16(afr[i], bfr[j], acc[i][j], 0, 0, 0);
    __builtin_amdgcn_s_setprio(0);
  };

  const int KT = (ID / 4) / 64;            // 16
  stage6(0, 0);
  WAITV(0);
  __builtin_amdgcn_s_barrier();
  for (int t = 0; t < KT; ++t) {
    const int cur = t & 1;
    if (t + 1 < KT) stage6(cur ^ 1, t + 1);
    computeKK(cur, 0);
    computeKK(cur, 1);
    WAITV(0);
    __builtin_amdgcn_s_barrier();
  }

  #pragma unroll
  for (int i = 0; i < 8; ++i)
    #pragma unroll
    for (int r = 0; r < 4; ++r) {
      const int mm = m0 + 128*wr + 16*i + 4*l4 + r;
      if (mm < nE) {
        const int id = pair[offE + mm];
        #pragma unroll
        for (int j = 0; j < 2; ++j)
          yb[(size_t)id * HD + n0 + 32*wc + 16*j + l15] = (_Float16)acc[i][j][r];
      }
    }
}

// ---------------- combine: out[t] = w0*sum_h(y[h][2t]) + w1*sum_h(y[h][2t+1])
__global__ void k_combine(const char* __restrict__ ws, float* __restrict__ out) {
  const int idx = blockIdx.x * blockDim.x + threadIdx.x;   // over T*HD/8
  const int t = idx >> 7, c = idx & 127;
  const float* topw = (const float*)(ws + WS_TOPW);
  const _Float16* yb = (const _Float16*)(ws + WS_YB);
  float s0[8] = {}, s1[8] = {};
  #pragma unroll
  for (int h = 0; h < 4; ++h) {
    const _Float16* p = yb + (size_t)h * TOTP * HD;
    f16x8 y0 = ((const f16x8*)(p + (size_t)(2*t)     * HD))[c];
    f16x8 y1 = ((const f16x8*)(p + (size_t)(2*t + 1) * HD))[c];
    #pragma unroll
    for (int j = 0; j < 8; ++j) { s0[j] += (float)y0[j]; s1[j] += (float)y1[j]; }
  }
  const float w0 = topw[2*t], w1 = topw[2*t+1];
  f32x4 o0, o1;
  #pragma unroll
  for (int j = 0; j < 4; ++j) {
    o0[j] = w0 * s0[j]     + w1 * s1[j];
    o1[j] = w0 * s0[4 + j] + w1 * s1[4 + j];
  }
  ((f32x4*)out)[2*idx]     = o0;
  ((f32x4*)out)[2*idx + 1] = o1;
}

extern "C" void kernel_launch(void* const* d_in, const int* in_sizes, int n_in,
                              void* d_out, int out_size, void* d_ws, size_t ws_size,
                              hipStream_t stream) {
  const float* hs     = (const float*)d_in[0];
  const float* logits = (const float*)d_in[1];
  const float* Wg     = (const float*)d_in[2];
  const float* Wu     = (const float*)d_in[3];
  const float* Wd     = (const float*)d_in[4];
  char* ws = (char*)d_ws;   // requires ~295 MB of workspace

  _Float16* hs16 = (_Float16*)(ws + WS_HS16);
  _Float16* wg16 = (_Float16*)(ws + WS_WG16);
  _Float16* wu16 = (_Float16*)(ws + WS_WU16);
  _Float16* wd16 = (_Float16*)(ws + WS_WD16);

  hipMemsetAsync(ws, 0, 256, stream);
  k_router <<<dim3(T_TOK/256), dim3(256), 0, stream>>>(logits, ws);
  k_prefix <<<dim3(1),         dim3(64),  0, stream>>>(ws);
  k_scatter<<<dim3(T_TOK/256), dim3(256), 0, stream>>>(ws);
  k_hscvt  <<<dim3(T_TOK*HD/8/256), dim3(256), 0, stream>>>(hs, hs16);
  k_wtrans <<<dim3(ID/64, HD/64, NE), dim3(256), 0, stream>>>(Wg, wg16, HD, ID);
  k_wtrans <<<dim3(ID/64, HD/64, NE), dim3(256), 0, stream>>>(Wu, wu16, HD, ID);
  k_wtrans <<<dim3(HD/64, ID/64, NE), dim3(256), 0, stream>>>(Wd, wd16, ID, HD);
  k_gemm1  <<<dim3(ID/128, MAXT2),    dim3(512), 0, stream>>>(hs16, wg16, wu16, ws);
  k_gemm2  <<<dim3(HD/128, MAXT2, 4), dim3(512), 0, stream>>>(wd16, ws);
  k_combine<<<dim3(T_TOK*HD/8/256), dim3(256), 0, stream>>>(ws, (float*)d_out);
}

// Round 13
// 505.628 us; speedup vs baseline: 1.2165x; 1.0003x over previous
//
#include <hip/hip_runtime.h>

typedef float    f32x4 __attribute__((ext_vector_type(4)));
typedef _Float16 f16x8 __attribute__((ext_vector_type(8)));
typedef _Float16 f16x4 __attribute__((ext_vector_type(4)));

#define T_TOK 4096
#define HD    1024
#define ID    4096
#define NE    8
#define TOTP  (2*T_TOK)
#define MAXT1 72
#define MAXT2 40     // BM=256 tiles (gemm1 + gemm2)

// ---- workspace layout (bytes). Total ~295 MB ----
#define WS_CNT   0
#define WS_FILL  64
#define WS_OFF   128
#define WS_TOT   192
#define WS_TOT2  196
#define WS_TEXP  256
#define WS_TM0   (256 + 4*MAXT1)
#define WS_TEXP2 (256 + 8*MAXT1)
#define WS_TM02  (256 + 8*MAXT1 + 4*MAXT2)
#define WS_TOPE  2048
#define WS_TOPW  (WS_TOPE + 4*TOTP)
#define WS_PAIR  (WS_TOPW + 4*TOTP)
#define WS_ACT   ((size_t)1 << 20)                              // f16[TOTP*ID]   64 MB
constexpr size_t WS_YBUF = WS_ACT  + 2ull*TOTP*ID;              // (spare)        16 MB
constexpr size_t WS_HS16 = WS_YBUF + 2ull*TOTP*HD;              // f16[T*HD]       8 MB
constexpr size_t WS_WG16 = WS_HS16 + 2ull*T_TOK*HD;             // f16[E][I][H]   67 MB
constexpr size_t WS_WU16 = WS_WG16 + 2ull*NE*HD*ID;             // f16[E][I][H]   67 MB
constexpr size_t WS_WD16 = WS_WU16 + 2ull*NE*HD*ID;             // f16[E][H][I]   67 MB
// 4 ybuf K-split partials overlay the Wg16 region (dead after gemm1): exact fit
constexpr size_t WS_YB   = WS_WG16;                             // f16[4][TOTP*HD]

// async global->LDS, 16B per lane, wave-uniform LDS base
__device__ __forceinline__ void gll16(const void* g, void* l) {
  __builtin_amdgcn_global_load_lds(
      (const __attribute__((address_space(1))) unsigned int*)g,
      (__attribute__((address_space(3))) unsigned int*)l, 16, 0, 0);
}

#define WAITV(N) do { \
    asm volatile("s_waitcnt vmcnt(" #N ")" ::: "memory"); \
    __builtin_amdgcn_sched_barrier(0); \
  } while (0)

// [row][64] f16 tile swizzle (BK=64): 8 granules XOR row&7 (bases 8-aligned)
__device__ __forceinline__ int lofs64(int row, int g8) {
  return row * 64 + ((g8 ^ (row & 7)) << 3);
}

// ---------------- routing ----------------
__global__ void k_router(const float* __restrict__ logits, char* __restrict__ ws) {
  int t = blockIdx.x * blockDim.x + threadIdx.x;
  if (t >= T_TOK) return;
  float v0 = -1e30f, v1 = -1e30f; int i0 = 0, i1 = 0;
  #pragma unroll
  for (int e = 0; e < NE; ++e) {
    float v = logits[t * NE + e];
    if (v > v0)      { v1 = v0; i1 = i0; v0 = v; i0 = e; }
    else if (v > v1) { v1 = v;  i1 = e; }
  }
  float w0 = 1.f / (1.f + __expf(v1 - v0));
  ((int*)(ws + WS_TOPE))[2*t]   = i0;
  ((int*)(ws + WS_TOPE))[2*t+1] = i1;
  ((float*)(ws + WS_TOPW))[2*t]   = w0;
  ((float*)(ws + WS_TOPW))[2*t+1] = 1.f - w0;
  atomicAdd(&((int*)(ws + WS_CNT))[i0], 1);
  atomicAdd(&((int*)(ws + WS_CNT))[i1], 1);
}

__global__ void k_prefix(char* __restrict__ ws) {
  if (threadIdx.x != 0 || blockIdx.x != 0) return;
  const int* cnt = (const int*)(ws + WS_CNT);
  int* off   = (int*)(ws + WS_OFF);
  int* texp  = (int*)(ws + WS_TEXP);
  int* tm0   = (int*)(ws + WS_TM0);
  int* texp2 = (int*)(ws + WS_TEXP2);
  int* tm02  = (int*)(ws + WS_TM02);
  int run = 0, t1 = 0, t2 = 0;
  for (int e = 0; e < NE; ++e) {
    off[e] = run;
    int ne = cnt[e];
    for (int i = 0; i < ne; i += 128) { texp[t1] = e; tm0[t1] = i; ++t1; }
    for (int i = 0; i < ne; i += 256) { texp2[t2] = e; tm02[t2] = i; ++t2; }
    run += ne;
  }
  off[NE] = run;
  *(int*)(ws + WS_TOT)  = t1;
  *(int*)(ws + WS_TOT2) = t2;
}

__global__ void k_scatter(char* __restrict__ ws) {
  int t = blockIdx.x * blockDim.x + threadIdx.x;
  if (t >= T_TOK) return;
  const int* tope = (const int*)(ws + WS_TOPE);
  const int* off  = (const int*)(ws + WS_OFF);
  int* fill = (int*)(ws + WS_FILL);
  int* pair = (int*)(ws + WS_PAIR);
  #pragma unroll
  for (int s = 0; s < 2; ++s) {
    int id = 2*t + s;
    int e = tope[id];
    int pos = off[e] + atomicAdd(&fill[e], 1);
    pair[pos] = id;   // order nondeterministic; ybuf row = id keeps output deterministic
  }
}

// ---------------- conversions ----------------
__global__ void k_hscvt(const float* __restrict__ src, _Float16* __restrict__ dst) {
  int i = blockIdx.x * blockDim.x + threadIdx.x;   // over T*HD/8
  f32x4 a = ((const f32x4*)src)[2*i];
  f32x4 b = ((const f32x4*)src)[2*i + 1];
  f16x8 o;
  #pragma unroll
  for (int j = 0; j < 4; ++j) { o[j] = (_Float16)a[j]; o[4 + j] = (_Float16)b[j]; }
  ((f16x8*)dst)[i] = o;
}

// f32 [e][K][N] -> f16 [e][N][K], 64x64 tiles via LDS; 16B reads AND writes
__global__ __launch_bounds__(256) void k_wtrans(const float* __restrict__ src,
                                                _Float16* __restrict__ dst,
                                                int K, int N) {
  const int e = blockIdx.z;
  const int n0 = blockIdx.x * 64, k0 = blockIdx.y * 64;
  const float* s = src + (size_t)e * K * N;
  _Float16* d = dst + (size_t)e * (size_t)K * N;
  __shared__ _Float16 t[64][72];   // 144B row stride: f16x8 reads stay 16B-aligned
  const int tx = threadIdx.x & 15, ty = threadIdx.x >> 4;
  #pragma unroll
  for (int it = 0; it < 4; ++it) {
    int k = k0 + it*16 + ty;
    f32x4 v = *(const f32x4*)&s[(size_t)k * N + n0 + tx*4];
    #pragma unroll
    for (int j = 0; j < 4; ++j) t[tx*4 + j][it*16 + ty] = (_Float16)v[j];
  }
  __syncthreads();
  const int n2 = threadIdx.x >> 3, sg = threadIdx.x & 7;
  #pragma unroll
  for (int it = 0; it < 2; ++it) {
    int n = it*32 + n2;
    *(f16x8*)&d[(size_t)(n0 + n) * K + k0 + sg*8] = *(const f16x8*)&t[n][sg*8];
  }
}

// ---------------- GEMM1: act[p] = silu(hs@Wg) * (hs@Wu), f16 ----------------
// (R9 structure, measured 177 us / MfmaUtil 38%)
// BM=256, BN=128 dual-B, BK=64; 8 waves (2M x 4N), wave tile 128x32 for g AND u.
__global__ __launch_bounds__(512, 2) void k_gemm1(
    const _Float16* __restrict__ hs16, const _Float16* __restrict__ WgT,
    const _Float16* __restrict__ WuT, char* __restrict__ ws) {
  const int s = blockIdx.y;
  if (s >= *(const int*)(ws + WS_TOT2)) return;
  const int e    = ((const int*)(ws + WS_TEXP2))[s];
  const int m0   = ((const int*)(ws + WS_TM02))[s];
  const int offE = ((const int*)(ws + WS_OFF))[e];
  const int nE   = ((const int*)(ws + WS_CNT))[e];
  _Float16* __restrict__ act = (_Float16*)(ws + WS_ACT);
  const int n0 = blockIdx.x * 128;
  const int tid = threadIdx.x, lane = tid & 63, wid = tid >> 6;

  // per buffer (f16 idx): A[256][64] @0 | Bg[128][64] @16384 | Bu[128][64] @24576
  __shared__ __align__(16) _Float16 sm[2 * 32768];   // 128 KB

  const int r8 = lane >> 3;
  const int q64 = (((lane & 7) ^ r8) << 3);   // inverse-swizzled source granule
  const int* __restrict__ pairp = (const int*)(ws + WS_PAIR);
  const _Float16 *aP[4], *gP[2], *uP[2];
  #pragma unroll
  for (int c = 0; c < 4; ++c) {        // A: wave stages rows 32w..32w+31
    int mm = m0 + 32*wid + 8*c + r8;
    int tok = (mm < nE) ? (pairp[offE + mm] >> 1) : 0;
    aP[c] = hs16 + (size_t)tok * HD + q64;
  }
  #pragma unroll
  for (int c = 0; c < 2; ++c) {        // B: wave stages cols 16w..16w+15
    size_t col = (size_t)e * ID + (n0 + 16*wid + 8*c + r8);
    gP[c] = WgT + col * HD + q64;
    uP[c] = WuT + col * HD + q64;
  }

  auto stage8 = [&](int buf, int kt) {   // 8 gll per wave per K-tile (128B lines)
    _Float16* base = sm + buf * 32768;
    const int ko = kt * 64;
    #pragma unroll
    for (int c = 0; c < 4; ++c)
      gll16(aP[c] + ko, base + (32*wid + 8*c) * 64);
    #pragma unroll
    for (int c = 0; c < 2; ++c) {
      gll16(gP[c] + ko, base + 16384 + (16*wid + 8*c) * 64);
      gll16(uP[c] + ko, base + 24576 + (16*wid + 8*c) * 64);
    }
  };

  const int wr = wid >> 2, wc = wid & 3;   // 2M x 4N
  const int l15 = lane & 15, l4 = lane >> 4;
  f32x4 accg[8][2] = {}, accu[8][2] = {};

  auto computeKK = [&](int buf, int kk) {  // one K=32 half: 12 reads, 32 MFMA
    const _Float16* b0 = sm + buf * 32768;
    f16x8 afr[8], bg[2], bu[2];
    #pragma unroll
    for (int i = 0; i < 8; ++i) {
      const int row = 128*wr + 16*i + l15;
      afr[i] = *(const f16x8*)&b0[lofs64(row, kk*4 + l4)];
    }
    #pragma unroll
    for (int j = 0; j < 2; ++j) {
      const int row = 32*wc + 16*j + l15;
      bg[j] = *(const f16x8*)&b0[16384 + lofs64(row, kk*4 + l4)];
      bu[j] = *(const f16x8*)&b0[24576 + lofs64(row, kk*4 + l4)];
    }
    __builtin_amdgcn_s_setprio(1);
    #pragma unroll
    for (int i = 0; i < 8; ++i)
      #pragma unroll
      for (int j = 0; j < 2; ++j) {
        accg[i][j] = __builtin_amdgcn_mfma_f32_16x16x32_f16(afr[i], bg[j], accg[i][j], 0, 0, 0);
        accu[i][j] = __builtin_amdgcn_mfma_f32_16x16x32_f16(afr[i], bu[j], accu[i][j], 0, 0, 0);
      }
    __builtin_amdgcn_s_setprio(0);
  };

  const int KT = HD / 64;                  // 16
  stage8(0, 0);
  WAITV(0);
  __builtin_amdgcn_s_barrier();
  for (int t = 0; t < KT; ++t) {
    const int cur = t & 1;
    if (t + 1 < KT) stage8(cur ^ 1, t + 1);  // issue early; retires under MFMA
    computeKK(cur, 0);
    computeKK(cur, 1);
    WAITV(0);                                // next tile fully landed
    __builtin_amdgcn_s_barrier();            // + everyone done reading cur
  }

  #pragma unroll
  for (int i = 0; i < 8; ++i)
    #pragma unroll
    for (int r = 0; r < 4; ++r) {
      const int mm = m0 + 128*wr + 16*i + 4*l4 + r;   // C/D: col=lane&15, row=(lane>>4)*4+r
      if (mm < nE) {
        const size_t prow = (size_t)(offE + mm) * ID;
        #pragma unroll
        for (int j = 0; j < 2; ++j) {
          float g = accg[i][j][r], u = accu[i][j][r];
          float sv = g / (1.f + __expf(-g)) * u;
          act[prow + n0 + 32*wc + 16*j + l15] = (_Float16)sv;
        }
      }
    }
}

// ---------------- GEMM2: yb[h][id] = act[p][kq] @ WdT[e][kq] (K-split 4) -----
// gemm1's proven shape at BN=128: BM=256, BK=64; 8 waves (2M x 4N), wave tile
// 128x32; 96 KB dbuf; 8*34*4 ~ 1088 blocks -> fine-grained makespan (+18% not +41%).
__global__ __launch_bounds__(512, 2) void k_gemm2(const _Float16* __restrict__ WdT,
                                                  char* __restrict__ ws) {
  const int s = blockIdx.y;
  if (s >= *(const int*)(ws + WS_TOT2)) return;
  const int e    = ((const int*)(ws + WS_TEXP2))[s];
  const int m0   = ((const int*)(ws + WS_TM02))[s];
  const int offE = ((const int*)(ws + WS_OFF))[e];
  const int nE   = ((const int*)(ws + WS_CNT))[e];
  const int h    = blockIdx.z;             // K quarter
  const int kbase = h * (ID / 4);
  const int* __restrict__ pair = (const int*)(ws + WS_PAIR);
  const _Float16* __restrict__ act = (const _Float16*)(ws + WS_ACT);
  _Float16* __restrict__ yb = (_Float16*)(ws + WS_YB) + (size_t)h * TOTP * HD;
  const int n0 = blockIdx.x * 128;
  const int tid = threadIdx.x, lane = tid & 63, wid = tid >> 6;

  // per buffer (f16 idx): A[256][64] @0 | B[128][64] @16384  -> 48 KB, dbuf 96 KB
  __shared__ __align__(16) _Float16 sm[2 * 24576];

  const int r8 = lane >> 3;
  const int q64 = (((lane & 7) ^ r8) << 3);
  const _Float16 *aP[4], *bP[2];
  #pragma unroll
  for (int c = 0; c < 4; ++c) {        // A: wave stages rows 32w..32w+31
    int mm = m0 + 32*wid + 8*c + r8;
    int p = (mm < nE) ? (offE + mm) : offE;   // act rows ARE pair positions
    aP[c] = act + (size_t)p * ID + kbase + q64;
  }
  #pragma unroll
  for (int c = 0; c < 2; ++c)          // B: wave stages cols 16w..16w+15
    bP[c] = WdT + ((size_t)e * HD + (n0 + 16*wid + 8*c + r8)) * ID + kbase + q64;

  auto stage6 = [&](int buf, int kt) {   // 6 gll per wave per K-tile (128B lines)
    _Float16* base = sm + buf * 24576;
    const int ko = kt * 64;
    #pragma unroll
    for (int c = 0; c < 4; ++c)
      gll16(aP[c] + ko, base + (32*wid + 8*c) * 64);
    #pragma unroll
    for (int c = 0; c < 2; ++c)
      gll16(bP[c] + ko, base + 16384 + (16*wid + 8*c) * 64);
  };

  const int wr = wid >> 2, wc = wid & 3;   // 2M x 4N
  const int l15 = lane & 15, l4 = lane >> 4;
  f32x4 acc[8][2] = {};

  auto computeKK = [&](int buf, int kk) {  // one K=32 half: 10 reads, 16 MFMA
    const _Float16* b0 = sm + buf * 24576;
    f16x8 afr[8], bfr[2];
    #pragma unroll
    for (int i = 0; i < 8; ++i)
      afr[i] = *(const f16x8*)&b0[lofs64(128*wr + 16*i + l15, kk*4 + l4)];
    #pragma unroll
    for (int j = 0; j < 2; ++j)
      bfr[j] = *(const f16x8*)&b0[16384 + lofs64(32*wc + 16*j + l15, kk*4 + l4)];
    __builtin_amdgcn_s_setprio(1);
    #pragma unroll
    for (int i = 0; i < 8; ++i)
      #pragma unroll
      for (int j = 0; j < 2; ++j)
        acc[i][j] = __builtin_amdgcn_mfma_f32_16x16x32_f16(afr[i], bfr[j], acc[i][j], 0, 0, 0);
    __builtin_amdgcn_s_setprio(0);
  };

  const int KT = (ID / 4) / 64;            // 16
  stage6(0, 0);
  WAITV(0);
  __builtin_amdgcn_s_barrier();
  for (int t = 0; t < KT; ++t) {
    const int cur = t & 1;
    if (t + 1 < KT) stage6(cur ^ 1, t + 1);
    computeKK(cur, 0);
    computeKK(cur, 1);
    WAITV(0);
    __builtin_amdgcn_s_barrier();
  }

  #pragma unroll
  for (int i = 0; i < 8; ++i)
    #pragma unroll
    for (int r = 0; r < 4; ++r) {
      const int mm = m0 + 128*wr + 16*i + 4*l4 + r;
      if (mm < nE) {
        const int id = pair[offE + mm];
        #pragma unroll
        for (int j = 0; j < 2; ++j)
          yb[(size_t)id * HD + n0 + 32*wc + 16*j + l15] = (_Float16)acc[i][j][r];
      }
    }
}

// ---------------- combine: out[t] = w0*sum_h(y[h][2t]) + w1*sum_h(y[h][2t+1])
__global__ void k_combine(const char* __restrict__ ws, float* __restrict__ out) {
  const int idx = blockIdx.x * blockDim.x + threadIdx.x;   // over T*HD/8
  const int t = idx >> 7, c = idx & 127;
  const float* topw = (const float*)(ws + WS_TOPW);
  const _Float16* yb = (const _Float16*)(ws + WS_YB);
  float s0[8] = {}, s1[8] = {};
  #pragma unroll
  for (int h = 0; h < 4; ++h) {
    const _Float16* p = yb + (size_t)h * TOTP * HD;
    f16x8 y0 = ((const f16x8*)(p + (size_t)(2*t)     * HD))[c];
    f16x8 y1 = ((const f16x8*)(p + (size_t)(2*t + 1) * HD))[c];
    #pragma unroll
    for (int j = 0; j < 8; ++j) { s0[j] += (float)y0[j]; s1[j] += (float)y1[j]; }
  }
  const float w0 = topw[2*t], w1 = topw[2*t+1];
  f32x4 o0, o1;
  #pragma unroll
  for (int j = 0; j < 4; ++j) {
    o0[j] = w0 * s0[j]     + w1 * s1[j];
    o1[j] = w0 * s0[4 + j] + w1 * s1[4 + j];
  }
  ((f32x4*)out)[2*idx]     = o0;
  ((f32x4*)out)[2*idx + 1] = o1;
}

extern "C" void kernel_launch(void* const* d_in, const int* in_sizes, int n_in,
                              void* d_out, int out_size, void* d_ws, size_t ws_size,
                              hipStream_t stream) {
  const float* hs     = (const float*)d_in[0];
  const float* logits = (const float*)d_in[1];
  const float* Wg     = (const float*)d_in[2];
  const float* Wu     = (const float*)d_in[3];
  const float* Wd     = (const float*)d_in[4];
  char* ws = (char*)d_ws;   // requires ~295 MB of workspace

  _Float16* hs16 = (_Float16*)(ws + WS_HS16);
  _Float16* wg16 = (_Float16*)(ws + WS_WG16);
  _Float16* wu16 = (_Float16*)(ws + WS_WU16);
  _Float16* wd16 = (_Float16*)(ws + WS_WD16);

  hipMemsetAsync(ws, 0, 256, stream);
  k_router <<<dim3(T_TOK/256), dim3(256), 0, stream>>>(logits, ws);
  k_prefix <<<dim3(1),         dim3(64),  0, stream>>>(ws);
  k_scatter<<<dim3(T_TOK/256), dim3(256), 0, stream>>>(ws);
  k_hscvt  <<<dim3(T_TOK*HD/8/256), dim3(256), 0, stream>>>(hs, hs16);
  k_wtrans <<<dim3(ID/64, HD/64, NE), dim3(256), 0, stream>>>(Wg, wg16, HD, ID);
  k_wtrans <<<dim3(ID/64, HD/64, NE), dim3(256), 0, stream>>>(Wu, wu16, HD, ID);
  k_wtrans <<<dim3(HD/64, ID/64, NE), dim3(256), 0, stream>>>(Wd, wd16, ID, HD);
  k_gemm1  <<<dim3(ID/128, MAXT2),    dim3(512), 0, stream>>>(hs16, wg16, wu16, ws);
  k_gemm2  <<<dim3(HD/128, MAXT2, 4), dim3(512), 0, stream>>>(wd16, ws);
  k_combine<<<dim3(T_TOK*HD/8/256), dim3(256), 0, stream>>>(ws, (float*)d_out);
}